// Round 16
// baseline (67.533 us; speedup 1.0000x reference)
//
#include <hip/hip_runtime.h>

#define WL 512   // window_len (t and o dims)
#define NV 64    // n_var
#define LR 16    // low rank
#define NB 512   // batch

__device__ __forceinline__ float tanh_fast(float x) {
    // tanh(x) = 1 - 2/(exp(2x)+1); exact at +-inf saturation, ~1e-7 abs err
    float e = __expf(2.0f * x);
    return 1.0f - 2.0f / (e + 1.0f);
}

// K1: tmp[b,v,k] = sum_t tanh(g[v]*x[b,t,v]) * A[t,k]   (TRANSPOSED [b,v,k])
// grid = 512 (one block per b), block = 1024 threads (16 waves).
// Hot loop = R7's verified version; epilogue = R12's transposed write
// (verified correct in R4/R12, absmax unchanged; R12/R13 deltas suggest
// K1+gap ~14.7us with this epilogue vs 16.5 for [b,k,v]).
__global__ __launch_bounds__(1024, 8) void k_tmp(
    const float* __restrict__ x, const float* __restrict__ gating,
    const float* __restrict__ A, float* __restrict__ tmp)
{
    __shared__ float red[16 * LR * 65];  // [tg][k][65] = 66.56 KiB, 2 blocks/CU
    const int tid = threadIdx.x;
    const int b = blockIdx.x;

    const int v = tid & 63;
    const int tg = __builtin_amdgcn_readfirstlane(tid >> 6);
    const float g = gating[v];

    float acc[LR];
#pragma unroll
    for (int k = 0; k < LR; ++k) acc[k] = 0.f;

    const float* xb = x + (size_t)b * (WL * NV) + (size_t)tg * 32 * NV + v;
    const float* Abase = A + (size_t)tg * 32 * LR;

#pragma unroll 4
    for (int i = 0; i < 32; ++i) {
        const float x1 = tanh_fast(g * xb[i * NV]);      // 256B/wave, coalesced
        const float* Ar = Abase + i * LR;                // wave-uniform -> s_load
#pragma unroll
        for (int k = 0; k < LR; ++k) acc[k] = fmaf(x1, Ar[k], acc[k]);
    }

    // write partials: lanes consecutive v, stride-1 -> conflict-free
#pragma unroll
    for (int k = 0; k < LR; ++k) red[(tg * LR + k) * 65 + v] = acc[k];
    __syncthreads();

    // one (v2,k2) pair per thread; t-ascending sum -> same order as always
    {
        const int p = tid;
        const int v2 = p >> 4;
        const int k2 = p & 15;
        float s = 0.f;
#pragma unroll
        for (int t = 0; t < 16; ++t) s += red[(t * LR + k2) * 65 + v2];
        tmp[(size_t)b * (LR * NV) + v2 * LR + k2] = s;   // [b][v][k], coalesced
    }
}

// K2: out[b,o,v] = x[b,o,v] + bias[o,v] + sum_k tmp[b,v,k]*B[k,o,v]
// PERSISTENT-BLOCK DECOMPOSITION: grid = 256 blocks (exactly 1/CU),
// block = 1024 threads (16 waves). Block owns o-rows {2*bid, 2*bid+1} for
// ALL 512 batches; wave w handles batches b = w, w+16, ..., w+496.
//
// Why (15 rounds of evidence): K2 is ~31us in EVERY structure; the knobs
// that varied (VMEM count, B source, occupancy, width) were never the
// binding term. The remaining terms are the 134MB x/out HBM floor plus
// re-read amplification (R2: 1.07GB B via L1; R15: 0.5GB tmp via L1/L2).
// This decomposition minimizes total bytes: B-slice 8KB -> register-
// resident at ~60 VGPR demand, UNDER the 64-VGPR half-grant measured in
// R6/R8 (allocator cannot force refetch); tmp read once per block
// (0.5GB L2 total, no intra-block duplication); x/out touched once.
// Per wave-batch: 8 VMEM (4 tmp-f4 + 2 x + 2 st). 16 waves/CU cover the
// ~700cy load->use chains (need ~14 at 50cy compute per iteration).
__global__ __launch_bounds__(1024, 4) void k_out(
    const float* __restrict__ x, const float* __restrict__ bias,
    const float* __restrict__ Bm, const float* __restrict__ tmp,
    float* __restrict__ out)
{
    const int tid = threadIdx.x;
    const int v = tid & 63;
    const int w = tid >> 6;                  // wave 0..15
    const int o0 = blockIdx.x * 2;           // block's 2 adjacent o-rows

    // B panel: 2 o-rows x 16 k for this lane's v. 64 dword loads, once ever.
    float Breg[2][LR];
#pragma unroll
    for (int j = 0; j < 2; ++j)
#pragma unroll
        for (int k = 0; k < LR; ++k)
            Breg[j][k] = Bm[((size_t)k * WL + (o0 + j)) * NV + v];  // coalesced

    float breg[2];
#pragma unroll
    for (int j = 0; j < 2; ++j) breg[j] = bias[(o0 + j) * NV + v];

#pragma unroll 1
    for (int bi = 0; bi < 32; ++bi) {
        const int b = w + bi * 16;           // wave-private batch

        // tmp row: 16 contiguous floats ([b,v,k]) = 4x float4, no duplication
        const float4* tb = (const float4*)(tmp + (size_t)b * (LR * NV) + v * LR);
        const float4 t0 = tb[0], t1 = tb[1], t2 = tb[2], t3 = tb[3];

        const float* xb = x + (size_t)b * (WL * NV) + (size_t)o0 * NV + v;
        const float x0 = xb[0];
        const float x1 = xb[NV];

        float* ob = out + (size_t)b * (WL * NV) + (size_t)o0 * NV + v;

#pragma unroll
        for (int j = 0; j < 2; ++j) {
            float acc = breg[j];
            acc = fmaf(t0.x, Breg[j][0],  acc);
            acc = fmaf(t0.y, Breg[j][1],  acc);
            acc = fmaf(t0.z, Breg[j][2],  acc);
            acc = fmaf(t0.w, Breg[j][3],  acc);
            acc = fmaf(t1.x, Breg[j][4],  acc);
            acc = fmaf(t1.y, Breg[j][5],  acc);
            acc = fmaf(t1.z, Breg[j][6],  acc);
            acc = fmaf(t1.w, Breg[j][7],  acc);
            acc = fmaf(t2.x, Breg[j][8],  acc);
            acc = fmaf(t2.y, Breg[j][9],  acc);
            acc = fmaf(t2.z, Breg[j][10], acc);
            acc = fmaf(t2.w, Breg[j][11], acc);
            acc = fmaf(t3.x, Breg[j][12], acc);
            acc = fmaf(t3.y, Breg[j][13], acc);
            acc = fmaf(t3.z, Breg[j][14], acc);
            acc = fmaf(t3.w, Breg[j][15], acc);
            ob[j * NV] = (j == 0 ? x0 : x1) + acc;           // coalesced 256B/wave
        }
    }
}

extern "C" void kernel_launch(void* const* d_in, const int* in_sizes, int n_in,
                              void* d_out, int out_size, void* d_ws, size_t ws_size,
                              hipStream_t stream) {
    const float* x      = (const float*)d_in[0];  // [512,512,64,1]
    const float* gating = (const float*)d_in[1];  // [64]
    const float* bias   = (const float*)d_in[2];  // [512,64]
    const float* A      = (const float*)d_in[3];  // [512,16]
    const float* Bm     = (const float*)d_in[4];  // [16,512,64]
    float* out = (float*)d_out;
    float* tmp = (float*)d_ws;                    // 2 MiB scratch ([b,v,k])

    k_tmp<<<NB, 1024, 0, stream>>>(x, gating, A, tmp);
    k_out<<<256, 1024, 0, stream>>>(x, bias, Bm, tmp, out);
}